// Round 1
// baseline (292.767 us; speedup 1.0000x reference)
//
#include <hip/hip_runtime.h>
#include <hip/hip_bf16.h>

// HierarchicalMambaBlock: B=2,T=1024,DIM=512 -> D_INNER=1024, DT_RANK=64, D_STATE=16
// All tensors f32. GEMMs on MFMA via split precision (hi/lo bf16, 3 MFMAs:
// Ah*Bh + Al*Bh + Ah*Bl). THIS VERSION: splits are hoisted out of the GEMM
// k-loop. A prologue kernel pre-splits x + all weights once per launch;
// producer epilogues (xproj, cg1, cg2) emit hi/lo pairs directly. GEMM
// staging is then a pure uint2 copy (no per-tile VALU split, half the bytes).
// Scan: CHUNK=32, fold-in-pass2, j-dimension split across 2 block groups (8
// states each, 896 blocks/pass); partials recombined by combine_y.
#define BATCH   2
#define SEQ     1024
#define DIMSZ   512
#define DINNER  1024
#define DTRANK  64
#define DSTATE  16
#define CHUNK   32

typedef __hip_bfloat16 bf16;
typedef __attribute__((ext_vector_type(8))) short s8v;   // 8 bf16 MFMA frag
typedef __attribute__((ext_vector_type(4))) float f4v;   // 4 f32 acc

// bf16 split-workspace offsets (bf16 elements, relative to bws)
// hi buffer immediately followed by lo buffer of the same size.
constexpr size_t OXH    = 0;          // x           2048x512
constexpr size_t OXL    = 1048576;
constexpr size_t OIPWH  = 2097152;    // in_proj_w   2048x512
constexpr size_t OIPWL  = 3145728;
constexpr size_t OXWH   = 4194304;    // xproj_w     3x96x1024
constexpr size_t OXWL   = 4489216;
constexpr size_t ODTWH  = 4784128;    // dtproj_w    3x1024x64
constexpr size_t ODTWL  = 4980736;
constexpr size_t OCG1H  = 5177344;    // cg_w1       512x1024
constexpr size_t OCG1L  = 5701632;
constexpr size_t OCG2H  = 6225920;    // cg_w2       1024x512
constexpr size_t OCG2L  = 6750208;
constexpr size_t OOPWH  = 7274496;    // out_proj_w  512x1024
constexpr size_t OOPWL  = 7798784;
constexpr size_t OPJDTH = 8323072;    // pj dt-cols  3584x64   (written by xproj)
constexpr size_t OPJDTL = 8552448;
constexpr size_t OH1H   = 8781824;    // h1          2048x512  (written by cg1)
constexpr size_t OH1L   = 9830400;
constexpr size_t OFGH   = 10878976;   // fusedg      2048x1024 (written by cg2)
constexpr size_t OFGL   = 12976128;
// end: 15,073,280 bf16 = 30.1 MB; f32 region 95.6 MB; total 125.7 MB < 256 MB ws

__device__ __forceinline__ float sigmoidf_(float x) { return 1.f / (1.f + __expf(-x)); }
__device__ __forceinline__ float siluf_(float x) { return x * sigmoidf_(x); }
__device__ __forceinline__ void split2(float v, bf16& hi, bf16& lo) {
    hi = __float2bfloat16(v);
    lo = __float2bfloat16(v - __bfloat162float(hi));
}
__device__ __forceinline__ void split_store4(const float4 v,
                                             bf16* __restrict__ ph,
                                             bf16* __restrict__ pl) {
    union { bf16 b[4]; uint2 u; } H, L;
    split2(v.x, H.b[0], L.b[0]); split2(v.y, H.b[1], L.b[1]);
    split2(v.z, H.b[2], L.b[2]); split2(v.w, H.b[3], L.b[3]);
    *reinterpret_cast<uint2*>(ph) = H.u;
    *reinterpret_cast<uint2*>(pl) = L.u;
}

// ---------------------------------------------------------------------------
// Prologue: split x + all weights into persistent bf16 hi/lo pairs.
// 4064 blocks x 256 threads x 4 elems.
// ---------------------------------------------------------------------------
__global__ void split_inputs_kernel(
    const float* __restrict__ x,   const float* __restrict__ ipw,
    const float* __restrict__ xw,  const float* __restrict__ dtw,
    const float* __restrict__ c1,  const float* __restrict__ c2,
    const float* __restrict__ opw, bf16* __restrict__ bws)
{
    int blk = blockIdx.x;
    const float* src; size_t off, sz;
    if (blk < 1024)      { src = x;   off = OXH;   sz = 1048576; }
    else if (blk < 2048) { src = ipw; off = OIPWH; sz = 1048576; blk -= 1024; }
    else if (blk < 2336) { src = xw;  off = OXWH;  sz = 294912;  blk -= 2048; }
    else if (blk < 2528) { src = dtw; off = ODTWH; sz = 196608;  blk -= 2336; }
    else if (blk < 3040) { src = c1;  off = OCG1H; sz = 524288;  blk -= 2528; }
    else if (blk < 3552) { src = c2;  off = OCG2H; sz = 524288;  blk -= 3040; }
    else                 { src = opw; off = OOPWH; sz = 524288;  blk -= 3552; }
    int i = blk * 1024 + threadIdx.x * 4;
    float4 v = *reinterpret_cast<const float4*>(src + i);
    split_store4(v, bws + off + i, bws + off + sz + i);
}

// ---------------------------------------------------------------------------
// MFMA GEMM, 64x64 tile, BK=64, 4 waves (each 32x32 of 16x16x32 frags),
// register prefetch of next K-tile. A/B are PRE-SPLIT bf16 hi/lo (pure-copy
// staging) except CTX_A which computes the f32 ctx average and splits inline.
// ACT: 0 none, 1 silu, 2 sigmoid, 3 bias+softplus
// DT_MODE: stacked dtproj (M=3584): per-block W/bias select by scale
// CTX_A:   A[m,k] = (y0[m,k] + y1[up(m),k] + y2[up(m),k]) / 3   (cg1 fusion)
// GATE3:   v = softmax_fused(y0,y1,y2,sw)[gm,gn] * v * silu(xz gate)
// OUT_SPLIT: write hi/lo bf16 pair (Ch/Cl) instead of f32 C.
// Requires: M,N multiples of 64, K multiple of 64, lda%4==0.
// ---------------------------------------------------------------------------
template <int ACT, bool ADD_RES, bool DT_MODE, bool CTX_A, bool GATE3, bool OUT_SPLIT>
__global__ __launch_bounds__(256) void mgemm_kernel(
    const bf16* __restrict__ Agh, const bf16* __restrict__ Agl, int lda, int K,
    const bf16* __restrict__ Bgh, const bf16* __restrict__ Bgl,
    const float* __restrict__ bias,
    const float* __restrict__ res,          // residual (ADD_RES)
    const float* __restrict__ gxz,          // xz (GATE3)
    const float* __restrict__ yy0,          // CTX_A / GATE3 (combined y per scale)
    const float* __restrict__ yy1,
    const float* __restrict__ yy2,
    const float* __restrict__ swp,          // GATE3 softmax weights (3)
    float* __restrict__ C, bf16* __restrict__ Ch, bf16* __restrict__ Cl, int N)
{
    __shared__ bf16 Ah[64][72], Al[64][72], Bh[64][72], Bl[64][72];

    const int m0 = blockIdx.x * 64;
    const int n0 = blockIdx.y * 64;
    const int tid = threadIdx.x;
    const int wave = tid >> 6;
    const int lane = tid & 63;
    const int wm = (wave >> 1) * 32;
    const int wn = (wave & 1) * 32;
    const int m16 = lane & 15;
    const int q   = lane >> 4;

    int scale = 0;
    if (DT_MODE) scale = (m0 < 2048) ? 0 : ((m0 < 3072) ? 1 : 2);
    const bf16* Bhp = DT_MODE ? (Bgh + (size_t)scale * 1024 * K) : Bgh;
    const bf16* Blp = DT_MODE ? (Bgl + (size_t)scale * 1024 * K) : Bgl;
    const float* bias_p = (ACT == 3) ? (DT_MODE ? bias + (size_t)scale * N : bias) : nullptr;

    f4v acc[2][2];
#pragma unroll
    for (int i = 0; i < 2; i++)
#pragma unroll
        for (int j = 0; j < 2; j++)
#pragma unroll
            for (int r = 0; r < 4; r++) acc[i][j][r] = 0.f;

    const int cch = tid & 15;
    const int c4  = cch * 4;
    const int r0  = tid >> 4;

    // A row pointers
    const float* a0p[4]; const float* a1p[4]; const float* a2p[4];
    const bf16*  ahp[4]; const bf16*  alp[4];
#pragma unroll
    for (int p = 0; p < 4; p++) {
        int m = m0 + r0 + p * 16;
        if (CTX_A) {
            int b = m >> 10, t = m & 1023;
            a0p[p] = yy0 + (size_t)m * 1024 + c4;
            a1p[p] = yy1 + (size_t)((b << 9) + (t >> 1)) * 1024 + c4;
            a2p[p] = yy2 + (size_t)((b << 8) + (t >> 2)) * 1024 + c4;
        } else {
            ahp[p] = Agh + (size_t)m * lda + c4;
            alp[p] = Agl + (size_t)m * lda + c4;
        }
    }
    const bf16* Bh_b = Bhp + (size_t)(n0 + r0) * K + c4;
    const bf16* Bl_b = Blp + (size_t)(n0 + r0) * K + c4;

    const int nkt = K >> 6;
    float4 raf[4]; uint2 rah[4], ral[4], rbh[4], rbl[4];
#pragma unroll
    for (int p = 0; p < 4; p++) {
        if (CTX_A) {
            float4 u = *reinterpret_cast<const float4*>(a0p[p]);
            float4 v = *reinterpret_cast<const float4*>(a1p[p]);
            float4 w = *reinterpret_cast<const float4*>(a2p[p]);
            raf[p] = make_float4((u.x + v.x + w.x) * (1.f / 3.f), (u.y + v.y + w.y) * (1.f / 3.f),
                                 (u.z + v.z + w.z) * (1.f / 3.f), (u.w + v.w + w.w) * (1.f / 3.f));
        } else {
            rah[p] = *reinterpret_cast<const uint2*>(ahp[p]);
            ral[p] = *reinterpret_cast<const uint2*>(alp[p]);
        }
        rbh[p] = *reinterpret_cast<const uint2*>(Bh_b + (size_t)(p * 16) * K);
        rbl[p] = *reinterpret_cast<const uint2*>(Bl_b + (size_t)(p * 16) * K);
    }

    for (int kt = 0; kt < nkt; kt++) {
        if (kt) __syncthreads();
#pragma unroll
        for (int p = 0; p < 4; p++) {
            int r = r0 + p * 16;
            if (CTX_A) {
                split_store4(raf[p], &Ah[r][c4], &Al[r][c4]);
            } else {
                *reinterpret_cast<uint2*>(&Ah[r][c4]) = rah[p];
                *reinterpret_cast<uint2*>(&Al[r][c4]) = ral[p];
            }
            *reinterpret_cast<uint2*>(&Bh[r][c4]) = rbh[p];
            *reinterpret_cast<uint2*>(&Bl[r][c4]) = rbl[p];
        }
        __syncthreads();
        if (kt + 1 < nkt) {
            int off = (kt + 1) * 64;
#pragma unroll
            for (int p = 0; p < 4; p++) {
                if (CTX_A) {
                    float4 u = *reinterpret_cast<const float4*>(a0p[p] + off);
                    float4 v = *reinterpret_cast<const float4*>(a1p[p] + off);
                    float4 w = *reinterpret_cast<const float4*>(a2p[p] + off);
                    raf[p] = make_float4((u.x + v.x + w.x) * (1.f / 3.f), (u.y + v.y + w.y) * (1.f / 3.f),
                                         (u.z + v.z + w.z) * (1.f / 3.f), (u.w + v.w + w.w) * (1.f / 3.f));
                } else {
                    rah[p] = *reinterpret_cast<const uint2*>(ahp[p] + off);
                    ral[p] = *reinterpret_cast<const uint2*>(alp[p] + off);
                }
                rbh[p] = *reinterpret_cast<const uint2*>(Bh_b + off + (size_t)(p * 16) * K);
                rbl[p] = *reinterpret_cast<const uint2*>(Bl_b + off + (size_t)(p * 16) * K);
            }
        }
#pragma unroll
        for (int kk = 0; kk < 2; kk++) {
            const int col = kk * 32 + q * 8;
            s8v ah[2], al[2], bh[2], bl[2];
#pragma unroll
            for (int i = 0; i < 2; i++) {
                int ar = wm + i * 16 + m16;
                ah[i] = *reinterpret_cast<const s8v*>(&Ah[ar][col]);
                al[i] = *reinterpret_cast<const s8v*>(&Al[ar][col]);
                int br = wn + i * 16 + m16;
                bh[i] = *reinterpret_cast<const s8v*>(&Bh[br][col]);
                bl[i] = *reinterpret_cast<const s8v*>(&Bl[br][col]);
            }
#pragma unroll
            for (int i = 0; i < 2; i++)
#pragma unroll
                for (int j = 0; j < 2; j++) {
                    acc[i][j] = __builtin_amdgcn_mfma_f32_16x16x32_bf16(ah[i], bh[j], acc[i][j], 0, 0, 0);
                    acc[i][j] = __builtin_amdgcn_mfma_f32_16x16x32_bf16(al[i], bh[j], acc[i][j], 0, 0, 0);
                    acc[i][j] = __builtin_amdgcn_mfma_f32_16x16x32_bf16(ah[i], bl[j], acc[i][j], 0, 0, 0);
                }
        }
    }

    // GATE3 softmax weights
    float e0 = 0.f, e1 = 0.f, e2 = 0.f, inv = 0.f;
    if (GATE3) {
        float s0 = swp[0], s1 = swp[1], s2 = swp[2];
        float mx = fmaxf(s0, fmaxf(s1, s2));
        e0 = __expf(s0 - mx); e1 = __expf(s1 - mx); e2 = __expf(s2 - mx);
        inv = 1.f / (e0 + e1 + e2);
    }

    // Epilogue. D mapping (verified): row = q*4 + reg, col = lane&15.
#pragma unroll
    for (int i = 0; i < 2; i++) {
#pragma unroll
        for (int j = 0; j < 2; j++) {
#pragma unroll
            for (int r = 0; r < 4; r++) {
                int gm = m0 + wm + i * 16 + q * 4 + r;
                int gn = n0 + wn + j * 16 + m16;
                float v = acc[i][j][r];
                if (ACT == 3) { v += bias_p[gn]; v = (v > 20.f) ? v : __logf(1.f + __expf(v)); }
                else if (ACT == 1) v = siluf_(v);
                else if (ACT == 2) v = sigmoidf_(v);
                if (GATE3) {
                    int b = gm >> 10, t = gm & 1023;
                    float f = (e0 * yy0[(size_t)gm * 1024 + gn]
                             + e1 * yy1[(size_t)((b << 9) + (t >> 1)) * 1024 + gn]
                             + e2 * yy2[(size_t)((b << 8) + (t >> 2)) * 1024 + gn]) * inv;
                    v = f * v * siluf_(gxz[(size_t)gm * 2048 + 1024 + gn]);
                } else if (ADD_RES) {
                    v += res[(size_t)gm * N + gn];
                }
                if (OUT_SPLIT) {
                    bf16 hh, ll; split2(v, hh, ll);
                    Ch[(size_t)gm * N + gn] = hh;
                    Cl[(size_t)gm * N + gn] = ll;
                } else {
                    C[(size_t)gm * N + gn] = v;
                }
            }
        }
    }
}

// ---------------------------------------------------------------------------
// xproj MFMA: stacked M=3584, N=96 (clamped), K=1024, ldc=96. Grid (56,2).
// A (xc) f32 split inline; B (xproj_w) pre-split. Epilogue also writes the
// dt columns (gn<64) as a dense pre-split 3584x64 pair for the dtproj GEMM.
// ---------------------------------------------------------------------------
__global__ __launch_bounds__(256) void xproj_mfma_kernel(
    const float* __restrict__ A,
    const bf16* __restrict__ xwh, const bf16* __restrict__ xwl,
    float* __restrict__ pj, bf16* __restrict__ pjdth, bf16* __restrict__ pjdtl)
{
    const int K = 1024;
    __shared__ bf16 Ah[64][72], Al[64][72], Bh[64][72], Bl[64][72];

    const int m0 = blockIdx.x * 64;
    const int n0 = blockIdx.y * 64;
    const int tid = threadIdx.x;
    const int wave = tid >> 6;
    const int lane = tid & 63;
    const int wm = (wave >> 1) * 32;
    const int wn = (wave & 1) * 32;
    const int m16 = lane & 15;
    const int q   = lane >> 4;

    const int scale = (m0 < 2048) ? 0 : ((m0 < 3072) ? 1 : 2);
    const bf16* Bhp = xwh + (size_t)scale * 96 * K;
    const bf16* Blp = xwl + (size_t)scale * 96 * K;

    f4v acc[2][2];
#pragma unroll
    for (int i = 0; i < 2; i++)
#pragma unroll
        for (int j = 0; j < 2; j++)
#pragma unroll
            for (int r = 0; r < 4; r++) acc[i][j][r] = 0.f;

    const int cch = tid & 15;
    const int c4  = cch * 4;
    const int r0  = tid >> 4;

    const float* Abase = A + (size_t)(m0 + r0) * K + c4;
    const bf16* Bh_b = Bhp + (size_t)(n0 + r0) * K + c4;
    const bf16* Bl_b = Blp + (size_t)(n0 + r0) * K + c4;
    bool bok[4];
#pragma unroll
    for (int p = 0; p < 4; p++) bok[p] = (n0 + r0 + p * 16) < 96;

    const int nkt = K >> 6;
    float4 ra[4]; uint2 rbh[4], rbl[4];
    const uint2 zero2 = make_uint2(0u, 0u);
#pragma unroll
    for (int p = 0; p < 4; p++) {
        ra[p] = *reinterpret_cast<const float4*>(Abase + (size_t)(p * 16) * K);
        rbh[p] = bok[p] ? *reinterpret_cast<const uint2*>(Bh_b + (size_t)(p * 16) * K) : zero2;
        rbl[p] = bok[p] ? *reinterpret_cast<const uint2*>(Bl_b + (size_t)(p * 16) * K) : zero2;
    }

    for (int kt = 0; kt < nkt; kt++) {
        if (kt) __syncthreads();
#pragma unroll
        for (int p = 0; p < 4; p++) {
            int r = r0 + p * 16;
            split_store4(ra[p], &Ah[r][c4], &Al[r][c4]);
            *reinterpret_cast<uint2*>(&Bh[r][c4]) = rbh[p];
            *reinterpret_cast<uint2*>(&Bl[r][c4]) = rbl[p];
        }
        __syncthreads();
        if (kt + 1 < nkt) {
            int off = (kt + 1) * 64;
#pragma unroll
            for (int p = 0; p < 4; p++) {
                ra[p] = *reinterpret_cast<const float4*>(Abase + off + (size_t)(p * 16) * K);
                rbh[p] = bok[p] ? *reinterpret_cast<const uint2*>(Bh_b + off + (size_t)(p * 16) * K) : zero2;
                rbl[p] = bok[p] ? *reinterpret_cast<const uint2*>(Bl_b + off + (size_t)(p * 16) * K) : zero2;
            }
        }
#pragma unroll
        for (int kk = 0; kk < 2; kk++) {
            const int col = kk * 32 + q * 8;
            s8v ah[2], al[2], bh[2], bl[2];
#pragma unroll
            for (int i = 0; i < 2; i++) {
                int ar = wm + i * 16 + m16;
                ah[i] = *reinterpret_cast<const s8v*>(&Ah[ar][col]);
                al[i] = *reinterpret_cast<const s8v*>(&Al[ar][col]);
                int br = wn + i * 16 + m16;
                bh[i] = *reinterpret_cast<const s8v*>(&Bh[br][col]);
                bl[i] = *reinterpret_cast<const s8v*>(&Bl[br][col]);
            }
#pragma unroll
            for (int i = 0; i < 2; i++)
#pragma unroll
                for (int j = 0; j < 2; j++) {
                    acc[i][j] = __builtin_amdgcn_mfma_f32_16x16x32_bf16(ah[i], bh[j], acc[i][j], 0, 0, 0);
                    acc[i][j] = __builtin_amdgcn_mfma_f32_16x16x32_bf16(al[i], bh[j], acc[i][j], 0, 0, 0);
                    acc[i][j] = __builtin_amdgcn_mfma_f32_16x16x32_bf16(ah[i], bl[j], acc[i][j], 0, 0, 0);
                }
        }
    }

#pragma unroll
    for (int i = 0; i < 2; i++) {
#pragma unroll
        for (int j = 0; j < 2; j++) {
            int gn = n0 + wn + j * 16 + m16;
            if (gn >= 96) continue;
#pragma unroll
            for (int r = 0; r < 4; r++) {
                int gm = m0 + wm + i * 16 + q * 4 + r;
                float v = acc[i][j][r];
                pj[(size_t)gm * 96 + gn] = v;
                if (gn < 64) {
                    bf16 hh, ll; split2(v, hh, ll);
                    pjdth[(size_t)gm * 64 + gn] = hh;
                    pjdtl[(size_t)gm * 64 + gn] = ll;
                }
            }
        }
    }
}

// ---------------------------------------------------------------------------
// Fused downsample + depthwise causal conv(K=4) + bias + SiLU, all 3 scales.
// ---------------------------------------------------------------------------
__global__ void conv_fused_kernel(const float* __restrict__ xz,
                                  const float* __restrict__ cw,
                                  const float* __restrict__ cb,
                                  float* __restrict__ xc)
{
    int idx = blockIdx.x * blockDim.x + threadIdx.x;
    if (idx >= 3670016) return;
    int s, rel;
    if (idx < 2097152)      { s = 0; rel = idx; }
    else if (idx < 3145728) { s = 1; rel = idx - 2097152; }
    else                    { s = 2; rel = idx - 3145728; }
    int c = rel & 1023;
    int row = rel >> 10;
    int Ts = 1024 >> s;
    int b = row / Ts;
    int t = row - b * Ts;
    const float* base = xz + (size_t)(b * 1024) * 2048 + c;

    float acc = cb[s * 1024 + c];
#pragma unroll
    for (int k = 0; k < 4; k++) {
        int tau = t - 3 + k;
        if (tau < 0) continue;
        float xv;
        if (s == 0) {
            xv = base[(size_t)tau * 2048];
        } else if (s == 1) {
            xv = 0.5f * (base[(size_t)(2 * tau) * 2048] + base[(size_t)(2 * tau + 1) * 2048]);
        } else {
            xv = 0.25f * (base[(size_t)(4 * tau) * 2048] + base[(size_t)(4 * tau + 1) * 2048]
                        + base[(size_t)(4 * tau + 2) * 2048] + base[(size_t)(4 * tau + 3) * 2048]);
        }
        acc = fmaf(cw[(s * 1024 + c) * 4 + k], xv, acc);
    }
    xc[idx] = siluf_(acc);
}

// ---------------------------------------------------------------------------
// Chunked selective scan — CHUNK=32, fold-in-pass2, j-split (8 states/block).
// 896 blocks per pass. State layout: [s][b][chunk][j][d] (d fastest).
// ---------------------------------------------------------------------------
__device__ __forceinline__ void scan_decode(int blk, int& s, int& nchunk, int& Ts,
                                            int& dquad, int& chunk, int& b, size_t& soff)
{
    int local;
    if (blk < 256)      { s = 0; local = blk;       soff = 0; }
    else if (blk < 384) { s = 1; local = blk - 256; soff = 1048576; }
    else                { s = 2; local = blk - 384; soff = 1572864; }
    nchunk = 32 >> s;
    Ts = 1024 >> s;
    dquad = local & 3;
    chunk = (local >> 2) & (nchunk - 1);
    b = local >> (7 - s);
}

__global__ __launch_bounds__(256) void scan_pass1(
    const float* __restrict__ dt0, const float* __restrict__ xc0, const float* __restrict__ pj0,
    const float* __restrict__ dt1, const float* __restrict__ xc1, const float* __restrict__ pj1,
    const float* __restrict__ dt2, const float* __restrict__ xc2, const float* __restrict__ pj2,
    const float* __restrict__ A_log,
    float* __restrict__ prodA_buf, float* __restrict__ h_buf)
{
    const int jhalf = (blockIdx.x >= 448) ? 1 : 0;
    const int jo = jhalf * 8;
    int s, nchunk, Ts, dquad, chunk, b; size_t soff;
    scan_decode(blockIdx.x - jhalf * 448, s, nchunk, Ts, dquad, chunk, b, soff);
    const float* dt = (s == 0) ? dt0 : (s == 1) ? dt1 : dt2;
    const float* xc = (s == 0) ? xc0 : (s == 1) ? xc1 : xc2;
    const float* pj = (s == 0) ? pj0 : (s == 1) ? pj1 : pj2;

    const int d = dquad * 256 + threadIdx.x;
    const size_t rowbase = (size_t)b * Ts;
    const int t0 = chunk * CHUNK;

    float Acoef[8], h[8], p[8];
#pragma unroll
    for (int j = 0; j < 8; j++) {
        Acoef[j] = -__expf(A_log[((size_t)(s * DINNER + d)) * 16 + jo + j]);
        h[j] = 0.f; p[j] = 1.f;
    }

    __shared__ float bcB[CHUNK][8];
    if (threadIdx.x < CHUNK * 8) {
        int i = threadIdx.x >> 3, jj = threadIdx.x & 7;
        bcB[i][jj] = pj[(rowbase + t0 + i) * 96 + 64 + jo + jj];
    }
    __syncthreads();

    for (int i = 0; i < CHUNK; i++) {
        size_t t = rowbase + t0 + i;
        float dtv = dt[t * DINNER + d];
        float xv  = xc[t * DINNER + d];
#pragma unroll
        for (int j = 0; j < 8; j++) {
            float dA  = fmaxf(__expf(dtv * Acoef[j]), 1e-38f);
            float dbx = fmaxf(dtv * bcB[i][j] * xv, 1e-38f);
            h[j] = fmaf(dA, h[j], dbx);
            p[j] *= dA;
        }
    }

    size_t base = soff + (size_t)((b * nchunk + chunk) * 16 + jo) * 1024 + d;
#pragma unroll
    for (int j = 0; j < 8; j++) {
        prodA_buf[base + (size_t)j * 1024] = p[j];
        h_buf[base + (size_t)j * 1024] = h[j];
    }
}

__global__ __launch_bounds__(256) void scan_pass2(
    const float* __restrict__ dt0, const float* __restrict__ xc0,
    const float* __restrict__ pj0,
    const float* __restrict__ dt1, const float* __restrict__ xc1,
    const float* __restrict__ pj1,
    const float* __restrict__ dt2, const float* __restrict__ xc2,
    const float* __restrict__ pj2,
    float* __restrict__ ya0, float* __restrict__ ya1, float* __restrict__ ya2,
    float* __restrict__ yb0, float* __restrict__ yb1, float* __restrict__ yb2,
    const float* __restrict__ A_log, const float* __restrict__ D_p,
    const float* __restrict__ prodA_buf, const float* __restrict__ h_buf)
{
    const int jhalf = (blockIdx.x >= 448) ? 1 : 0;
    const int jo = jhalf * 8;
    int s, nchunk, Ts, dquad, chunk, b; size_t soff;
    scan_decode(blockIdx.x - jhalf * 448, s, nchunk, Ts, dquad, chunk, b, soff);
    const float* dt = (s == 0) ? dt0 : (s == 1) ? dt1 : dt2;
    const float* xc = (s == 0) ? xc0 : (s == 1) ? xc1 : xc2;
    const float* pj = (s == 0) ? pj0 : (s == 1) ? pj1 : pj2;
    float* y = jhalf ? ((s == 0) ? yb0 : (s == 1) ? yb1 : yb2)
                     : ((s == 0) ? ya0 : (s == 1) ? ya1 : ya2);

    const int d = dquad * 256 + threadIdx.x;
    const size_t rowbase = (size_t)b * Ts;
    const int t0 = chunk * CHUNK;

    float Acoef[8], h[8];
#pragma unroll
    for (int j = 0; j < 8; j++) {
        Acoef[j] = -__expf(A_log[((size_t)(s * DINNER + d)) * 16 + jo + j]);
        h[j] = 0.f;
    }
    const float Dp = (jhalf == 0) ? D_p[s * DINNER + d] : 0.f;

    // carry-in: fold predecessor chunk states for our 8 j's (read-only)
    for (int c = 0; c < chunk; c++) {
        size_t cb = soff + (size_t)((b * nchunk + c) * 16 + jo) * 1024 + d;
#pragma unroll
        for (int j = 0; j < 8; j++)
            h[j] = fmaf(prodA_buf[cb + (size_t)j * 1024], h[j], h_buf[cb + (size_t)j * 1024]);
    }

    __shared__ float bc[CHUNK][16];   // B (0..7) and C (8..15) for our 8 j's
    for (int u = threadIdx.x; u < CHUNK * 16; u += 256) {
        int i = u >> 4, jj = u & 15;
        int col = (jj < 8) ? (64 + jo + jj) : (80 + jo + (jj - 8));
        bc[i][jj] = pj[(rowbase + t0 + i) * 96 + col];
    }
    __syncthreads();

    for (int i = 0; i < CHUNK; i++) {
        size_t t = rowbase + t0 + i;
        float dtv = dt[t * DINNER + d];
        float xv  = xc[t * DINNER + d];
        float accy = 0.f;
#pragma unroll
        for (int j = 0; j < 8; j++) {
            float dA  = fmaxf(__expf(dtv * Acoef[j]), 1e-38f);
            float dbx = fmaxf(dtv * bc[i][j] * xv, 1e-38f);
            h[j] = fmaf(dA, h[j], dbx);
            accy = fmaf(bc[i][8 + j], h[j], accy);
        }
        y[t * DINNER + d] = accy + Dp * xv;
    }
}

// ---------------------------------------------------------------------------
// combine_y: ysum = yA + yB (contiguous 3,670,016 floats each, float4 vec).
// ---------------------------------------------------------------------------
__global__ void combine_y_kernel(const float* __restrict__ ya,
                                 const float* __restrict__ yb,
                                 float* __restrict__ ysum)
{
    int idx = blockIdx.x * blockDim.x + threadIdx.x;   // 917,504 float4s
    float4 a = reinterpret_cast<const float4*>(ya)[idx];
    float4 b = reinterpret_cast<const float4*>(yb)[idx];
    reinterpret_cast<float4*>(ysum)[idx] =
        make_float4(a.x + b.x, a.y + b.y, a.z + b.z, a.w + b.w);
}

// ---------------------------------------------------------------------------
__global__ __launch_bounds__(256) void ln_kernel(
    const float* __restrict__ yin, const float* __restrict__ gamma,
    const float* __restrict__ beta, float* __restrict__ out)
{
    int token = blockIdx.x;
    int tid = threadIdx.x;
    const float* row = yin + (size_t)token * DIMSZ;
    float v0 = row[tid], v1 = row[tid + 256];
    __shared__ float s1[256], s2[256];
    s1[tid] = v0 + v1;
    s2[tid] = v0 * v0 + v1 * v1;
    __syncthreads();
    for (int off = 128; off > 0; off >>= 1) {
        if (tid < off) { s1[tid] += s1[tid + off]; s2[tid] += s2[tid + off]; }
        __syncthreads();
    }
    float mu = s1[0] * (1.f / 512.f);
    float var = s2[0] * (1.f / 512.f) - mu * mu;
    float rstd = rsqrtf(var + 1e-5f);
    float* orow = out + (size_t)token * DIMSZ;
    orow[tid]       = (v0 - mu) * rstd * gamma[tid]       + beta[tid];
    orow[tid + 256] = (v1 - mu) * rstd * gamma[tid + 256] + beta[tid + 256];
}

// ---------------------------------------------------------------------------
extern "C" void kernel_launch(void* const* d_in, const int* in_sizes, int n_in,
                              void* d_out, int out_size, void* d_ws, size_t ws_size,
                              hipStream_t stream)
{
    const float* x         = (const float*)d_in[0];
    const float* in_proj_w = (const float*)d_in[1];
    const float* conv_w    = (const float*)d_in[2];
    const float* conv_b    = (const float*)d_in[3];
    const float* xproj_w   = (const float*)d_in[4];
    const float* dtproj_w  = (const float*)d_in[5];
    const float* dtproj_b  = (const float*)d_in[6];
    const float* A_log     = (const float*)d_in[7];
    const float* D_p       = (const float*)d_in[8];
    const float* scale_w   = (const float*)d_in[9];
    const float* cg_w1     = (const float*)d_in[10];
    const float* cg_w2     = (const float*)d_in[11];
    const float* out_pw    = (const float*)d_in[12];
    const float* ln_gamma  = (const float*)d_in[13];
    const float* ln_beta   = (const float*)d_in[14];
    float* out = (float*)d_out;

    float* ws = (float*)d_ws;
    // f32 workspace layout (element offsets)
    float* xz    = ws;                       // 4,194,304  (2048 x 2048)
    float* xc0   = xz    + 4194304;          // xc stacked 3584x1024
    float* xc1   = xc0   + 2097152;
    float* xc2   = xc1   + 1048576;
    float* pj0   = xc2   + 524288;           // pj stacked 3584x96
    float* pj1   = pj0   + 196608;
    float* pj2   = pj1   + 98304;
    float* dt0   = pj2   + 49152;            // dt stacked 3584x1024
    float* dt1   = dt0   + 2097152;
    float* dt2   = dt1   + 1048576;
    float* ya0   = dt2   + 524288;           // y partial A (j<8), contiguous
    float* ya1   = ya0   + 2097152;
    float* ya2   = ya1   + 1048576;
    float* yb0   = ya2   + 524288;           // y partial B (j>=8), contiguous
    float* yb1   = yb0   + 2097152;
    float* yb2   = yb1   + 1048576;
    float* prodA = yb2   + 524288;           // 1,835,008 (CHUNK=32 states)
    float* hbuf  = prodA + 1835008;          // 1,835,008
    // f32 total: 23,887,872 floats = 95.6 MB

    // bf16 split workspace (after f32 region; 16B-aligned)
    bf16* bws = (bf16*)(ws + 23887872);
    const bf16 *xh   = bws + OXH,   *xl   = bws + OXL;
    const bf16 *ipwh = bws + OIPWH, *ipwl = bws + OIPWL;
    const bf16 *xwh  = bws + OXWH,  *xwl  = bws + OXWL;
    const bf16 *dtwh = bws + ODTWH, *dtwl = bws + ODTWL;
    const bf16 *cg1h = bws + OCG1H, *cg1l = bws + OCG1L;
    const bf16 *cg2h = bws + OCG2H, *cg2l = bws + OCG2L;
    const bf16 *opwh = bws + OOPWH, *opwl = bws + OOPWL;
    bf16 *pjdth = bws + OPJDTH, *pjdtl = bws + OPJDTL;
    bf16 *h1h   = bws + OH1H,   *h1l   = bws + OH1L;
    bf16 *fgh   = bws + OFGH,   *fgl   = bws + OFGL;

    // Overlays (lifetime-checked; all strictly produce-then-consume):
    float* ysum0  = dt0;                  // combined y (dt dead after pass2)
    float* ysum1  = dt0 + 2097152;
    float* ysum2  = dt0 + 3145728;
    float* outpre = prodA;                // out_proj out (prodA dead after pass2)

    // P0) pre-split x + all weights into bf16 hi/lo — 4064 blocks
    split_inputs_kernel<<<4064, 256, 0, stream>>>(
        x, in_proj_w, xproj_w, dtproj_w, cg_w1, cg_w2, out_pw, bws);

    // P1) in_proj: xz = x @ in_proj_w^T  (M=2048,N=2048,K=512) — 1024 blocks
    mgemm_kernel<0, false, false, false, false, false><<<dim3(32, 32), 256, 0, stream>>>(
        xh, xl, DIMSZ, DIMSZ, ipwh, ipwl, nullptr, nullptr, nullptr,
        nullptr, nullptr, nullptr, nullptr, xz, nullptr, nullptr, 2048);

    // P2) fused downsample+conv+SiLU — 14336 blocks
    conv_fused_kernel<<<14336, 256, 0, stream>>>(xz, conv_w, conv_b, xc0);

    // P3) xproj stacked MFMA (M=3584,N=96,K=1024) — 112 blocks; emits pjdt split
    xproj_mfma_kernel<<<dim3(56, 2), 256, 0, stream>>>(xc0, xwh, xwl, pj0, pjdth, pjdtl);

    // P4) dtproj stacked (M=3584,N=1024,K=64, A=pjdt split) — 896 blocks
    mgemm_kernel<3, false, true, false, false, false><<<dim3(56, 16), 256, 0, stream>>>(
        pjdth, pjdtl, DTRANK, DTRANK, dtwh, dtwl, dtproj_b, nullptr, nullptr,
        nullptr, nullptr, nullptr, nullptr, dt0, nullptr, nullptr, 1024);

    // P5/P6) chunked selective scan, j-split — 896 blocks each
    scan_pass1<<<896, 256, 0, stream>>>(dt0, xc0, pj0, dt1, xc1, pj1,
                                        dt2, xc2, pj2, A_log, prodA, hbuf);
    scan_pass2<<<896, 256, 0, stream>>>(dt0, xc0, pj0, dt1, xc1, pj1,
                                        dt2, xc2, pj2,
                                        ya0, ya1, ya2, yb0, yb1, yb2,
                                        A_log, D_p, prodA, hbuf);

    // P7) combine partials: ysum = yA + yB — 3584 blocks (float4)
    combine_y_kernel<<<3584, 256, 0, stream>>>(ya0, yb0, ysum0);

    // P8) cg1 (ctx on-the-fly from ysum): h1 = silu(ctx @ cg_w1^T), OUT_SPLIT
    //     (N=512,K=1024) — 256 blocks
    mgemm_kernel<1, false, false, true, false, true><<<dim3(32, 8), 256, 0, stream>>>(
        nullptr, nullptr, DINNER, DINNER, cg1h, cg1l, nullptr, nullptr, nullptr,
        ysum0, ysum1, ysum2, nullptr, nullptr, h1h, h1l, 512);

    // P9) cg2 + softmax-fuse + gate: fusedg = fused(ysum,sw)*sigmoid(h1@cg_w2^T)*silu(gate)
    //     A = h1 split, OUT_SPLIT (N=1024,K=512) — 512 blocks
    mgemm_kernel<2, false, false, false, true, true><<<dim3(32, 16), 256, 0, stream>>>(
        h1h, h1l, DIMSZ, DIMSZ, cg2h, cg2l, nullptr, nullptr, xz,
        ysum0, ysum1, ysum2, scale_w, nullptr, fgh, fgl, 1024);

    // P10) out_proj + residual: outpre = fusedg @ out_pw^T + x (N=512,K=1024)
    mgemm_kernel<0, true, false, false, false, false><<<dim3(32, 8), 256, 0, stream>>>(
        fgh, fgl, DINNER, DINNER, opwh, opwl, nullptr, x, nullptr,
        nullptr, nullptr, nullptr, nullptr, outpre, nullptr, nullptr, 512);

    // P11) LayerNorm
    ln_kernel<<<BATCH * SEQ, 256, 0, stream>>>(outpre, ln_gamma, ln_beta, out);
}

// Round 2
// 284.526 us; speedup vs baseline: 1.0290x; 1.0290x over previous
//
#include <hip/hip_runtime.h>
#include <hip/hip_bf16.h>

// HierarchicalMambaBlock: B=2,T=1024,DIM=512 -> D_INNER=1024, DT_RANK=64, D_STATE=16
// GEMMs on MFMA via split precision (hi/lo bf16, 3 MFMAs: Ah*Bh + Al*Bh + Ah*Bl).
// Split operands stored INTERLEAVED: each 4-f32 group -> [hi0..hi3|lo0..lo3]
// (16 B), so GEMM staging is ONE uint4 load per operand per lane (16 B
// coalescing sweet spot), no per-tile split VALU.
// Scan: CHUNK=32 pass1 (per-chunk states, j-split, 896 blocks) ->
// scan_prefix (exclusive prefix over chunks in-place, 384 blocks) ->
// pass2 unified 16-state (448 blocks) writing final y directly.
// No combine kernel, no O(nchunk^2) carry fold.
#define BATCH   2
#define SEQ     1024
#define DIMSZ   512
#define DINNER  1024
#define DTRANK  64
#define DSTATE  16
#define CHUNK   32

typedef __hip_bfloat16 bf16;
typedef __attribute__((ext_vector_type(8))) short s8v;   // 8 bf16 MFMA frag
typedef __attribute__((ext_vector_type(4))) float f4v;   // 4 f32 acc

// Interleaved bf16 split-workspace offsets (bf16 elements, relative to bws).
// Each tensor occupies 2x its f32 element count (hi+lo interleaved per 4-group).
constexpr size_t OXI   = 0;          // x           2048x512   -> 2,097,152
constexpr size_t OIPI  = 2097152;    // in_proj_w   2048x512   -> 2,097,152
constexpr size_t OXWI  = 4194304;    // xproj_w     3x96x1024  ->   589,824
constexpr size_t ODTI  = 4784128;    // dtproj_w    3x1024x64  ->   393,216
constexpr size_t OC1I  = 5177344;    // cg_w1       512x1024   -> 1,048,576
constexpr size_t OC2I  = 6225920;    // cg_w2       1024x512   -> 1,048,576
constexpr size_t OOPI  = 7274496;    // out_proj_w  512x1024   -> 1,048,576
constexpr size_t OPJI  = 8323072;    // pj dt-cols  3584x64    ->   458,752
constexpr size_t OH1I  = 8781824;    // h1          2048x512   -> 2,097,152
constexpr size_t OFGI  = 10878976;   // fusedg      2048x1024  -> 4,194,304
// end: 15,073,280 bf16 = 30.1 MB; f32 region 95.6 MB; total 125.7 MB < ws

__device__ __forceinline__ float sigmoidf_(float x) { return 1.f / (1.f + __expf(-x)); }
__device__ __forceinline__ float siluf_(float x) { return x * sigmoidf_(x); }
__device__ __forceinline__ void split2(float v, bf16& hi, bf16& lo) {
    hi = __float2bfloat16(v);
    lo = __float2bfloat16(v - __bfloat162float(hi));
}
// interleaved store: 4 f32 -> [hi4|lo4] (16 B) at p
__device__ __forceinline__ void split_store4i(const float4 v, bf16* __restrict__ p) {
    union { bf16 b[8]; uint4 q; } U;
    split2(v.x, U.b[0], U.b[4]); split2(v.y, U.b[1], U.b[5]);
    split2(v.z, U.b[2], U.b[6]); split2(v.w, U.b[3], U.b[7]);
    *reinterpret_cast<uint4*>(p) = U.q;
}
// LDS-stage split: 4 f32 -> separate hi/lo uint2 stores (CTX_A inline path)
__device__ __forceinline__ void split_store4(const float4 v,
                                             bf16* __restrict__ ph,
                                             bf16* __restrict__ pl) {
    union { bf16 b[4]; uint2 u; } H, L;
    split2(v.x, H.b[0], L.b[0]); split2(v.y, H.b[1], L.b[1]);
    split2(v.z, H.b[2], L.b[2]); split2(v.w, H.b[3], L.b[3]);
    *reinterpret_cast<uint2*>(ph) = H.u;
    *reinterpret_cast<uint2*>(pl) = L.u;
}

// ---------------------------------------------------------------------------
// Prologue: split x + all weights into persistent interleaved bf16 hi/lo.
// 4064 blocks x 256 threads x 4 f32 elems.
// ---------------------------------------------------------------------------
__global__ void split_inputs_kernel(
    const float* __restrict__ x,   const float* __restrict__ ipw,
    const float* __restrict__ xw,  const float* __restrict__ dtw,
    const float* __restrict__ c1,  const float* __restrict__ c2,
    const float* __restrict__ opw, bf16* __restrict__ bws)
{
    int blk = blockIdx.x;
    const float* src; size_t off;
    if (blk < 1024)      { src = x;   off = OXI;  }
    else if (blk < 2048) { src = ipw; off = OIPI; blk -= 1024; }
    else if (blk < 2336) { src = xw;  off = OXWI; blk -= 2048; }
    else if (blk < 2528) { src = dtw; off = ODTI; blk -= 2336; }
    else if (blk < 3040) { src = c1;  off = OC1I; blk -= 2528; }
    else if (blk < 3552) { src = c2;  off = OC2I; blk -= 3040; }
    else                 { src = opw; off = OOPI; blk -= 3552; }
    int i = blk * 1024 + threadIdx.x * 4;
    float4 v = *reinterpret_cast<const float4*>(src + i);
    split_store4i(v, bws + off + (size_t)i * 2);
}

// ---------------------------------------------------------------------------
// MFMA GEMM, 64x64 tile, BK=64, 4 waves (each 32x32 of 16x16x32 frags),
// register prefetch of next K-tile. A/B are interleaved pre-split bf16
// (one uint4 load -> uint2 hi + uint2 lo LDS stores), except CTX_A which
// computes the f32 ctx average and splits inline.
// ACT: 0 none, 1 silu, 2 sigmoid, 3 bias+softplus
// DT_MODE: stacked dtproj (M=3584): per-block W/bias select by scale
// CTX_A:   A[m,k] = (y0[m,k] + y1[up(m),k] + y2[up(m),k]) / 3   (cg1 fusion)
// GATE3:   v = softmax_fused(y0,y1,y2,sw)[gm,gn] * v * silu(xz gate)
// OUT_SPLIT: write interleaved hi/lo bf16 (Ci) instead of f32 C.
// Requires: M,N multiples of 64, K multiple of 64, lda%4==0.
// ---------------------------------------------------------------------------
template <int ACT, bool ADD_RES, bool DT_MODE, bool CTX_A, bool GATE3, bool OUT_SPLIT>
__global__ __launch_bounds__(256) void mgemm_kernel(
    const bf16* __restrict__ Ai, int lda, int K,
    const bf16* __restrict__ Bi,
    const float* __restrict__ bias,
    const float* __restrict__ res,          // residual (ADD_RES)
    const float* __restrict__ gxz,          // xz (GATE3)
    const float* __restrict__ yy0,          // CTX_A / GATE3 (y per scale)
    const float* __restrict__ yy1,
    const float* __restrict__ yy2,
    const float* __restrict__ swp,          // GATE3 softmax weights (3)
    float* __restrict__ C, bf16* __restrict__ Ci, int N)
{
    __shared__ bf16 Ah[64][72], Al[64][72], Bh[64][72], Bl[64][72];

    const int m0 = blockIdx.x * 64;
    const int n0 = blockIdx.y * 64;
    const int tid = threadIdx.x;
    const int wave = tid >> 6;
    const int lane = tid & 63;
    const int wm = (wave >> 1) * 32;
    const int wn = (wave & 1) * 32;
    const int m16 = lane & 15;
    const int q   = lane >> 4;

    int scale = 0;
    if (DT_MODE) scale = (m0 < 2048) ? 0 : ((m0 < 3072) ? 1 : 2);
    const bf16* Bip = DT_MODE ? (Bi + (size_t)scale * 1024 * K * 2) : Bi;
    const float* bias_p = (ACT == 3) ? (DT_MODE ? bias + (size_t)scale * N : bias) : nullptr;

    f4v acc[2][2];
#pragma unroll
    for (int i = 0; i < 2; i++)
#pragma unroll
        for (int j = 0; j < 2; j++)
#pragma unroll
            for (int r = 0; r < 4; r++) acc[i][j][r] = 0.f;

    const int cch = tid & 15;
    const int c4  = cch * 4;
    const int r0  = tid >> 4;

    // A row pointers
    const float* a0p[4]; const float* a1p[4]; const float* a2p[4];
    const bf16*  aip[4];
#pragma unroll
    for (int p = 0; p < 4; p++) {
        int m = m0 + r0 + p * 16;
        if (CTX_A) {
            int b = m >> 10, t = m & 1023;
            a0p[p] = yy0 + (size_t)m * 1024 + c4;
            a1p[p] = yy1 + (size_t)((b << 9) + (t >> 1)) * 1024 + c4;
            a2p[p] = yy2 + (size_t)((b << 8) + (t >> 2)) * 1024 + c4;
        } else {
            aip[p] = Ai + ((size_t)m * lda + c4) * 2;
        }
    }
    const bf16* Bi_b = Bip + ((size_t)(n0 + r0) * K + c4) * 2;

    const int nkt = K >> 6;
    float4 raf[4]; uint2 rah[4], ral[4], rbh[4], rbl[4];
#pragma unroll
    for (int p = 0; p < 4; p++) {
        if (CTX_A) {
            float4 u = *reinterpret_cast<const float4*>(a0p[p]);
            float4 v = *reinterpret_cast<const float4*>(a1p[p]);
            float4 w = *reinterpret_cast<const float4*>(a2p[p]);
            raf[p] = make_float4((u.x + v.x + w.x) * (1.f / 3.f), (u.y + v.y + w.y) * (1.f / 3.f),
                                 (u.z + v.z + w.z) * (1.f / 3.f), (u.w + v.w + w.w) * (1.f / 3.f));
        } else {
            uint4 ua = *reinterpret_cast<const uint4*>(aip[p]);
            rah[p] = make_uint2(ua.x, ua.y); ral[p] = make_uint2(ua.z, ua.w);
        }
        uint4 ub = *reinterpret_cast<const uint4*>(Bi_b + (size_t)(p * 16) * K * 2);
        rbh[p] = make_uint2(ub.x, ub.y); rbl[p] = make_uint2(ub.z, ub.w);
    }

    for (int kt = 0; kt < nkt; kt++) {
        if (kt) __syncthreads();
#pragma unroll
        for (int p = 0; p < 4; p++) {
            int r = r0 + p * 16;
            if (CTX_A) {
                split_store4(raf[p], &Ah[r][c4], &Al[r][c4]);
            } else {
                *reinterpret_cast<uint2*>(&Ah[r][c4]) = rah[p];
                *reinterpret_cast<uint2*>(&Al[r][c4]) = ral[p];
            }
            *reinterpret_cast<uint2*>(&Bh[r][c4]) = rbh[p];
            *reinterpret_cast<uint2*>(&Bl[r][c4]) = rbl[p];
        }
        __syncthreads();
        if (kt + 1 < nkt) {
            int off = (kt + 1) * 64;
#pragma unroll
            for (int p = 0; p < 4; p++) {
                if (CTX_A) {
                    float4 u = *reinterpret_cast<const float4*>(a0p[p] + off);
                    float4 v = *reinterpret_cast<const float4*>(a1p[p] + off);
                    float4 w = *reinterpret_cast<const float4*>(a2p[p] + off);
                    raf[p] = make_float4((u.x + v.x + w.x) * (1.f / 3.f), (u.y + v.y + w.y) * (1.f / 3.f),
                                         (u.z + v.z + w.z) * (1.f / 3.f), (u.w + v.w + w.w) * (1.f / 3.f));
                } else {
                    uint4 ua = *reinterpret_cast<const uint4*>(aip[p] + (size_t)off * 2);
                    rah[p] = make_uint2(ua.x, ua.y); ral[p] = make_uint2(ua.z, ua.w);
                }
                uint4 ub = *reinterpret_cast<const uint4*>(Bi_b + ((size_t)(p * 16) * K + off) * 2);
                rbh[p] = make_uint2(ub.x, ub.y); rbl[p] = make_uint2(ub.z, ub.w);
            }
        }
#pragma unroll
        for (int kk = 0; kk < 2; kk++) {
            const int col = kk * 32 + q * 8;
            s8v ah[2], al[2], bh[2], bl[2];
#pragma unroll
            for (int i = 0; i < 2; i++) {
                int ar = wm + i * 16 + m16;
                ah[i] = *reinterpret_cast<const s8v*>(&Ah[ar][col]);
                al[i] = *reinterpret_cast<const s8v*>(&Al[ar][col]);
                int br = wn + i * 16 + m16;
                bh[i] = *reinterpret_cast<const s8v*>(&Bh[br][col]);
                bl[i] = *reinterpret_cast<const s8v*>(&Bl[br][col]);
            }
#pragma unroll
            for (int i = 0; i < 2; i++)
#pragma unroll
                for (int j = 0; j < 2; j++) {
                    acc[i][j] = __builtin_amdgcn_mfma_f32_16x16x32_bf16(ah[i], bh[j], acc[i][j], 0, 0, 0);
                    acc[i][j] = __builtin_amdgcn_mfma_f32_16x16x32_bf16(al[i], bh[j], acc[i][j], 0, 0, 0);
                    acc[i][j] = __builtin_amdgcn_mfma_f32_16x16x32_bf16(ah[i], bl[j], acc[i][j], 0, 0, 0);
                }
        }
    }

    // GATE3 softmax weights
    float e0 = 0.f, e1 = 0.f, e2 = 0.f, inv = 0.f;
    if (GATE3) {
        float s0 = swp[0], s1 = swp[1], s2 = swp[2];
        float mx = fmaxf(s0, fmaxf(s1, s2));
        e0 = __expf(s0 - mx); e1 = __expf(s1 - mx); e2 = __expf(s2 - mx);
        inv = 1.f / (e0 + e1 + e2);
    }

    // Epilogue. D mapping (verified): row = q*4 + reg, col = lane&15.
#pragma unroll
    for (int i = 0; i < 2; i++) {
#pragma unroll
        for (int j = 0; j < 2; j++) {
#pragma unroll
            for (int r = 0; r < 4; r++) {
                int gm = m0 + wm + i * 16 + q * 4 + r;
                int gn = n0 + wn + j * 16 + m16;
                float v = acc[i][j][r];
                if (ACT == 3) { v += bias_p[gn]; v = (v > 20.f) ? v : __logf(1.f + __expf(v)); }
                else if (ACT == 1) v = siluf_(v);
                else if (ACT == 2) v = sigmoidf_(v);
                if (GATE3) {
                    int b = gm >> 10, t = gm & 1023;
                    float f = (e0 * yy0[(size_t)gm * 1024 + gn]
                             + e1 * yy1[(size_t)((b << 9) + (t >> 1)) * 1024 + gn]
                             + e2 * yy2[(size_t)((b << 8) + (t >> 2)) * 1024 + gn]) * inv;
                    v = f * v * siluf_(gxz[(size_t)gm * 2048 + 1024 + gn]);
                } else if (ADD_RES) {
                    v += res[(size_t)gm * N + gn];
                }
                if (OUT_SPLIT) {
                    bf16 hh, ll; split2(v, hh, ll);
                    size_t gb = ((size_t)gm * N + (gn & ~3)) * 2 + (gn & 3);
                    Ci[gb] = hh;
                    Ci[gb + 4] = ll;
                } else {
                    C[(size_t)gm * N + gn] = v;
                }
            }
        }
    }
}

// ---------------------------------------------------------------------------
// xproj MFMA: stacked M=3584, N=96 (clamped), K=1024, ldc=96. Grid (56,2).
// A (xc) f32 split inline; B (xproj_w) interleaved pre-split. Epilogue also
// writes the dt columns (gn<64) as interleaved 3584x64 split for dtproj.
// ---------------------------------------------------------------------------
__global__ __launch_bounds__(256) void xproj_mfma_kernel(
    const float* __restrict__ A,
    const bf16* __restrict__ xwi,
    float* __restrict__ pj, bf16* __restrict__ pjdti)
{
    const int K = 1024;
    __shared__ bf16 Ah[64][72], Al[64][72], Bh[64][72], Bl[64][72];

    const int m0 = blockIdx.x * 64;
    const int n0 = blockIdx.y * 64;
    const int tid = threadIdx.x;
    const int wave = tid >> 6;
    const int lane = tid & 63;
    const int wm = (wave >> 1) * 32;
    const int wn = (wave & 1) * 32;
    const int m16 = lane & 15;
    const int q   = lane >> 4;

    const int scale = (m0 < 2048) ? 0 : ((m0 < 3072) ? 1 : 2);
    const bf16* Bip = xwi + (size_t)scale * 96 * K * 2;

    f4v acc[2][2];
#pragma unroll
    for (int i = 0; i < 2; i++)
#pragma unroll
        for (int j = 0; j < 2; j++)
#pragma unroll
            for (int r = 0; r < 4; r++) acc[i][j][r] = 0.f;

    const int cch = tid & 15;
    const int c4  = cch * 4;
    const int r0  = tid >> 4;

    const float* Abase = A + (size_t)(m0 + r0) * K + c4;
    const bf16* Bi_b = Bip + ((size_t)(n0 + r0) * K + c4) * 2;
    bool bok[4];
#pragma unroll
    for (int p = 0; p < 4; p++) bok[p] = (n0 + r0 + p * 16) < 96;

    const int nkt = K >> 6;
    float4 ra[4]; uint2 rbh[4], rbl[4];
#pragma unroll
    for (int p = 0; p < 4; p++) {
        ra[p] = *reinterpret_cast<const float4*>(Abase + (size_t)(p * 16) * K);
        if (bok[p]) {
            uint4 ub = *reinterpret_cast<const uint4*>(Bi_b + (size_t)(p * 16) * K * 2);
            rbh[p] = make_uint2(ub.x, ub.y); rbl[p] = make_uint2(ub.z, ub.w);
        } else { rbh[p] = make_uint2(0u, 0u); rbl[p] = make_uint2(0u, 0u); }
    }

    for (int kt = 0; kt < nkt; kt++) {
        if (kt) __syncthreads();
#pragma unroll
        for (int p = 0; p < 4; p++) {
            int r = r0 + p * 16;
            split_store4(ra[p], &Ah[r][c4], &Al[r][c4]);
            *reinterpret_cast<uint2*>(&Bh[r][c4]) = rbh[p];
            *reinterpret_cast<uint2*>(&Bl[r][c4]) = rbl[p];
        }
        __syncthreads();
        if (kt + 1 < nkt) {
            int off = (kt + 1) * 64;
#pragma unroll
            for (int p = 0; p < 4; p++) {
                ra[p] = *reinterpret_cast<const float4*>(Abase + off + (size_t)(p * 16) * K);
                if (bok[p]) {
                    uint4 ub = *reinterpret_cast<const uint4*>(Bi_b + ((size_t)(p * 16) * K + off) * 2);
                    rbh[p] = make_uint2(ub.x, ub.y); rbl[p] = make_uint2(ub.z, ub.w);
                }
            }
        }
#pragma unroll
        for (int kk = 0; kk < 2; kk++) {
            const int col = kk * 32 + q * 8;
            s8v ah[2], al[2], bh[2], bl[2];
#pragma unroll
            for (int i = 0; i < 2; i++) {
                int ar = wm + i * 16 + m16;
                ah[i] = *reinterpret_cast<const s8v*>(&Ah[ar][col]);
                al[i] = *reinterpret_cast<const s8v*>(&Al[ar][col]);
                int br = wn + i * 16 + m16;
                bh[i] = *reinterpret_cast<const s8v*>(&Bh[br][col]);
                bl[i] = *reinterpret_cast<const s8v*>(&Bl[br][col]);
            }
#pragma unroll
            for (int i = 0; i < 2; i++)
#pragma unroll
                for (int j = 0; j < 2; j++) {
                    acc[i][j] = __builtin_amdgcn_mfma_f32_16x16x32_bf16(ah[i], bh[j], acc[i][j], 0, 0, 0);
                    acc[i][j] = __builtin_amdgcn_mfma_f32_16x16x32_bf16(al[i], bh[j], acc[i][j], 0, 0, 0);
                    acc[i][j] = __builtin_amdgcn_mfma_f32_16x16x32_bf16(ah[i], bl[j], acc[i][j], 0, 0, 0);
                }
        }
    }

#pragma unroll
    for (int i = 0; i < 2; i++) {
#pragma unroll
        for (int j = 0; j < 2; j++) {
            int gn = n0 + wn + j * 16 + m16;
            if (gn >= 96) continue;
#pragma unroll
            for (int r = 0; r < 4; r++) {
                int gm = m0 + wm + i * 16 + q * 4 + r;
                float v = acc[i][j][r];
                pj[(size_t)gm * 96 + gn] = v;
                if (gn < 64) {
                    bf16 hh, ll; split2(v, hh, ll);
                    size_t gb = ((size_t)gm * 64 + (gn & ~3)) * 2 + (gn & 3);
                    pjdti[gb] = hh;
                    pjdti[gb + 4] = ll;
                }
            }
        }
    }
}

// ---------------------------------------------------------------------------
// Fused downsample + depthwise causal conv(K=4) + bias + SiLU, all 3 scales.
// ---------------------------------------------------------------------------
__global__ void conv_fused_kernel(const float* __restrict__ xz,
                                  const float* __restrict__ cw,
                                  const float* __restrict__ cb,
                                  float* __restrict__ xc)
{
    int idx = blockIdx.x * blockDim.x + threadIdx.x;
    if (idx >= 3670016) return;
    int s, rel;
    if (idx < 2097152)      { s = 0; rel = idx; }
    else if (idx < 3145728) { s = 1; rel = idx - 2097152; }
    else                    { s = 2; rel = idx - 3145728; }
    int c = rel & 1023;
    int row = rel >> 10;
    int Ts = 1024 >> s;
    int b = row / Ts;
    int t = row - b * Ts;
    const float* base = xz + (size_t)(b * 1024) * 2048 + c;

    float acc = cb[s * 1024 + c];
#pragma unroll
    for (int k = 0; k < 4; k++) {
        int tau = t - 3 + k;
        if (tau < 0) continue;
        float xv;
        if (s == 0) {
            xv = base[(size_t)tau * 2048];
        } else if (s == 1) {
            xv = 0.5f * (base[(size_t)(2 * tau) * 2048] + base[(size_t)(2 * tau + 1) * 2048]);
        } else {
            xv = 0.25f * (base[(size_t)(4 * tau) * 2048] + base[(size_t)(4 * tau + 1) * 2048]
                        + base[(size_t)(4 * tau + 2) * 2048] + base[(size_t)(4 * tau + 3) * 2048]);
        }
        acc = fmaf(cw[(s * 1024 + c) * 4 + k], xv, acc);
    }
    xc[idx] = siluf_(acc);
}

// ---------------------------------------------------------------------------
// Chunked selective scan. State layout: [s][b][chunk][j][d] (d fastest).
// ---------------------------------------------------------------------------
__device__ __forceinline__ void scan_decode(int blk, int& s, int& nchunk, int& Ts,
                                            int& dquad, int& chunk, int& b, size_t& soff)
{
    int local;
    if (blk < 256)      { s = 0; local = blk;       soff = 0; }
    else if (blk < 384) { s = 1; local = blk - 256; soff = 1048576; }
    else                { s = 2; local = blk - 384; soff = 1572864; }
    nchunk = 32 >> s;
    Ts = 1024 >> s;
    dquad = local & 3;
    chunk = (local >> 2) & (nchunk - 1);
    b = local >> (7 - s);
}

// pass1: per-chunk (prodA, h) states; j-split (8 states/block), 896 blocks.
__global__ __launch_bounds__(256) void scan_pass1(
    const float* __restrict__ dt0, const float* __restrict__ xc0, const float* __restrict__ pj0,
    const float* __restrict__ dt1, const float* __restrict__ xc1, const float* __restrict__ pj1,
    const float* __restrict__ dt2, const float* __restrict__ xc2, const float* __restrict__ pj2,
    const float* __restrict__ A_log,
    float* __restrict__ prodA_buf, float* __restrict__ h_buf)
{
    const int jhalf = (blockIdx.x >= 448) ? 1 : 0;
    const int jo = jhalf * 8;
    int s, nchunk, Ts, dquad, chunk, b; size_t soff;
    scan_decode(blockIdx.x - jhalf * 448, s, nchunk, Ts, dquad, chunk, b, soff);
    const float* dt = (s == 0) ? dt0 : (s == 1) ? dt1 : dt2;
    const float* xc = (s == 0) ? xc0 : (s == 1) ? xc1 : xc2;
    const float* pj = (s == 0) ? pj0 : (s == 1) ? pj1 : pj2;

    const int d = dquad * 256 + threadIdx.x;
    const size_t rowbase = (size_t)b * Ts;
    const int t0 = chunk * CHUNK;

    float Acoef[8], h[8], p[8];
#pragma unroll
    for (int j = 0; j < 8; j++) {
        Acoef[j] = -__expf(A_log[((size_t)(s * DINNER + d)) * 16 + jo + j]);
        h[j] = 0.f; p[j] = 1.f;
    }

    __shared__ float bcB[CHUNK][8];
    if (threadIdx.x < CHUNK * 8) {
        int i = threadIdx.x >> 3, jj = threadIdx.x & 7;
        bcB[i][jj] = pj[(rowbase + t0 + i) * 96 + 64 + jo + jj];
    }
    __syncthreads();

    for (int i = 0; i < CHUNK; i++) {
        size_t t = rowbase + t0 + i;
        float dtv = dt[t * DINNER + d];
        float xv  = xc[t * DINNER + d];
#pragma unroll
        for (int j = 0; j < 8; j++) {
            float dA  = fmaxf(__expf(dtv * Acoef[j]), 1e-38f);
            float dbx = fmaxf(dtv * bcB[i][j] * xv, 1e-38f);
            h[j] = fmaf(dA, h[j], dbx);
            p[j] *= dA;
        }
    }

    size_t base = soff + (size_t)((b * nchunk + chunk) * 16 + jo) * 1024 + d;
#pragma unroll
    for (int j = 0; j < 8; j++) {
        prodA_buf[base + (size_t)j * 1024] = p[j];
        h_buf[base + (size_t)j * 1024] = h[j];
    }
}

// scan_prefix: in-place exclusive prefix over chunks: h_buf[c] <- H_excl(c).
// One thread per (s,b,j,d); 384 blocks x 256 threads; nchunk<=32 sequential.
__global__ __launch_bounds__(256) void scan_prefix_kernel(
    const float* __restrict__ prodA_buf, float* __restrict__ h_buf)
{
    int blk = blockIdx.x;
    int s; size_t soff;
    if (blk < 128)      { s = 0; soff = 0; }
    else if (blk < 256) { s = 1; soff = 1048576; blk -= 128; }
    else                { s = 2; soff = 1572864; blk -= 256; }
    const int nchunk = 32 >> s;
    const int b  = blk >> 6;          // local = b*64 + j*4 + dq
    const int j  = (blk >> 2) & 15;
    const int dq = blk & 3;
    const int d  = dq * 256 + threadIdx.x;

    float H = 0.f;
    for (int c = 0; c < nchunk; c++) {
        size_t idx = soff + (size_t)((b * nchunk + c) * 16 + j) * 1024 + d;
        float p = prodA_buf[idx];
        float h = h_buf[idx];
        h_buf[idx] = H;
        H = fmaf(p, H, h);
    }
}

// pass2: unified 16-state, O(1) carry (h_buf holds exclusive prefix),
// writes final y directly. 448 blocks.
__global__ __launch_bounds__(256) void scan_pass2(
    const float* __restrict__ dt0, const float* __restrict__ xc0,
    const float* __restrict__ pj0,
    const float* __restrict__ dt1, const float* __restrict__ xc1,
    const float* __restrict__ pj1,
    const float* __restrict__ dt2, const float* __restrict__ xc2,
    const float* __restrict__ pj2,
    float* __restrict__ y0, float* __restrict__ y1, float* __restrict__ y2,
    const float* __restrict__ A_log, const float* __restrict__ D_p,
    const float* __restrict__ carry)
{
    int s, nchunk, Ts, dquad, chunk, b; size_t soff;
    scan_decode(blockIdx.x, s, nchunk, Ts, dquad, chunk, b, soff);
    const float* dt = (s == 0) ? dt0 : (s == 1) ? dt1 : dt2;
    const float* xc = (s == 0) ? xc0 : (s == 1) ? xc1 : xc2;
    const float* pj = (s == 0) ? pj0 : (s == 1) ? pj1 : pj2;
    float* y = (s == 0) ? y0 : (s == 1) ? y1 : y2;

    const int d = dquad * 256 + threadIdx.x;
    const size_t rowbase = (size_t)b * Ts;
    const int t0 = chunk * CHUNK;

    float Acoef[16], h[16];
    const size_t cb = soff + (size_t)((b * nchunk + chunk) * 16) * 1024 + d;
#pragma unroll
    for (int j = 0; j < 16; j++) {
        Acoef[j] = -__expf(A_log[((size_t)(s * DINNER + d)) * 16 + j]);
        h[j] = carry[cb + (size_t)j * 1024];
    }
    const float Dp = D_p[s * DINNER + d];

    __shared__ float bc[CHUNK][32];   // B (0..15) and C (16..31)
    for (int u = threadIdx.x; u < CHUNK * 32; u += 256) {
        int i = u >> 5, jj = u & 31;
        bc[i][jj] = pj[(rowbase + t0 + i) * 96 + 64 + jj];
    }
    __syncthreads();

    for (int i = 0; i < CHUNK; i++) {
        size_t t = rowbase + t0 + i;
        float dtv = dt[t * DINNER + d];
        float xv  = xc[t * DINNER + d];
        float accy = 0.f;
#pragma unroll
        for (int j = 0; j < 16; j++) {
            float dA  = fmaxf(__expf(dtv * Acoef[j]), 1e-38f);
            float dbx = fmaxf(dtv * bc[i][j] * xv, 1e-38f);
            h[j] = fmaf(dA, h[j], dbx);
            accy = fmaf(bc[i][16 + j], h[j], accy);
        }
        y[t * DINNER + d] = accy + Dp * xv;
    }
}

// ---------------------------------------------------------------------------
__global__ __launch_bounds__(256) void ln_kernel(
    const float* __restrict__ yin, const float* __restrict__ gamma,
    const float* __restrict__ beta, float* __restrict__ out)
{
    int token = blockIdx.x;
    int tid = threadIdx.x;
    const float* row = yin + (size_t)token * DIMSZ;
    float v0 = row[tid], v1 = row[tid + 256];
    __shared__ float s1[256], s2[256];
    s1[tid] = v0 + v1;
    s2[tid] = v0 * v0 + v1 * v1;
    __syncthreads();
    for (int off = 128; off > 0; off >>= 1) {
        if (tid < off) { s1[tid] += s1[tid + off]; s2[tid] += s2[tid + off]; }
        __syncthreads();
    }
    float mu = s1[0] * (1.f / 512.f);
    float var = s2[0] * (1.f / 512.f) - mu * mu;
    float rstd = rsqrtf(var + 1e-5f);
    float* orow = out + (size_t)token * DIMSZ;
    orow[tid]       = (v0 - mu) * rstd * gamma[tid]       + beta[tid];
    orow[tid + 256] = (v1 - mu) * rstd * gamma[tid + 256] + beta[tid + 256];
}

// ---------------------------------------------------------------------------
extern "C" void kernel_launch(void* const* d_in, const int* in_sizes, int n_in,
                              void* d_out, int out_size, void* d_ws, size_t ws_size,
                              hipStream_t stream)
{
    const float* x         = (const float*)d_in[0];
    const float* in_proj_w = (const float*)d_in[1];
    const float* conv_w    = (const float*)d_in[2];
    const float* conv_b    = (const float*)d_in[3];
    const float* xproj_w   = (const float*)d_in[4];
    const float* dtproj_w  = (const float*)d_in[5];
    const float* dtproj_b  = (const float*)d_in[6];
    const float* A_log     = (const float*)d_in[7];
    const float* D_p       = (const float*)d_in[8];
    const float* scale_w   = (const float*)d_in[9];
    const float* cg_w1     = (const float*)d_in[10];
    const float* cg_w2     = (const float*)d_in[11];
    const float* out_pw    = (const float*)d_in[12];
    const float* ln_gamma  = (const float*)d_in[13];
    const float* ln_beta   = (const float*)d_in[14];
    float* out = (float*)d_out;

    float* ws = (float*)d_ws;
    // f32 workspace layout (element offsets)
    float* xz    = ws;                       // 4,194,304  (2048 x 2048)
    float* xc0   = xz    + 4194304;          // xc stacked 3584x1024
    float* xc1   = xc0   + 2097152;
    float* xc2   = xc1   + 1048576;
    float* pj0   = xc2   + 524288;           // pj stacked 3584x96
    float* pj1   = pj0   + 196608;
    float* pj2   = pj1   + 98304;
    float* dt0   = pj2   + 49152;            // dt stacked 3584x1024
    float* dt1   = dt0   + 2097152;
    float* dt2   = dt1   + 1048576;
    float* y0    = dt2   + 524288;           // final y per scale (contiguous)
    float* y1    = y0    + 2097152;
    float* y2    = y1    + 1048576;
    float* prodA = y2    + 524288 + 3670016; // (skip old yb region) per-chunk prodA
    float* hbuf  = prodA + 1835008;          // per-chunk h -> exclusive prefix
    // f32 total: 23,887,872 floats = 95.6 MB

    // bf16 interleaved split workspace (after f32 region; 16B-aligned)
    bf16* bws = (bf16*)(ws + 23887872);
    const bf16 *xi   = bws + OXI;
    const bf16 *ipwi = bws + OIPI;
    const bf16 *xwi  = bws + OXWI;
    const bf16 *dtwi = bws + ODTI;
    const bf16 *c1i  = bws + OC1I;
    const bf16 *c2i  = bws + OC2I;
    const bf16 *opwi = bws + OOPI;
    bf16 *pjdti = bws + OPJI;
    bf16 *h1i   = bws + OH1I;
    bf16 *fgi   = bws + OFGI;

    // Overlays (lifetime-checked):
    float* outpre = prodA;                // out_proj out (prodA dead after prefix)

    // P0) pre-split x + all weights into interleaved bf16 — 4064 blocks
    split_inputs_kernel<<<4064, 256, 0, stream>>>(
        x, in_proj_w, xproj_w, dtproj_w, cg_w1, cg_w2, out_pw, bws);

    // P1) in_proj: xz = x @ in_proj_w^T  (M=2048,N=2048,K=512) — 1024 blocks
    mgemm_kernel<0, false, false, false, false, false><<<dim3(32, 32), 256, 0, stream>>>(
        xi, DIMSZ, DIMSZ, ipwi, nullptr, nullptr, nullptr,
        nullptr, nullptr, nullptr, nullptr, xz, nullptr, 2048);

    // P2) fused downsample+conv+SiLU — 14336 blocks
    conv_fused_kernel<<<14336, 256, 0, stream>>>(xz, conv_w, conv_b, xc0);

    // P3) xproj stacked MFMA (M=3584,N=96,K=1024) — 112 blocks; emits pjdt split
    xproj_mfma_kernel<<<dim3(56, 2), 256, 0, stream>>>(xc0, xwi, pj0, pjdti);

    // P4) dtproj stacked (M=3584,N=1024,K=64, A=pjdt split) — 896 blocks
    mgemm_kernel<3, false, true, false, false, false><<<dim3(56, 16), 256, 0, stream>>>(
        pjdti, DTRANK, DTRANK, dtwi, dtproj_b, nullptr, nullptr,
        nullptr, nullptr, nullptr, nullptr, dt0, nullptr, 1024);

    // P5) scan pass1: per-chunk states, j-split — 896 blocks
    scan_pass1<<<896, 256, 0, stream>>>(dt0, xc0, pj0, dt1, xc1, pj1,
                                        dt2, xc2, pj2, A_log, prodA, hbuf);
    // P6) exclusive prefix over chunks (in-place on hbuf) — 384 blocks
    scan_prefix_kernel<<<384, 256, 0, stream>>>(prodA, hbuf);
    // P7) pass2: unified 16-state, final y — 448 blocks
    scan_pass2<<<448, 256, 0, stream>>>(dt0, xc0, pj0, dt1, xc1, pj1,
                                        dt2, xc2, pj2,
                                        y0, y1, y2, A_log, D_p, hbuf);

    // P8) cg1 (ctx on-the-fly from y): h1 = silu(ctx @ cg_w1^T), OUT_SPLIT
    //     (N=512,K=1024) — 256 blocks
    mgemm_kernel<1, false, false, true, false, true><<<dim3(32, 8), 256, 0, stream>>>(
        nullptr, DINNER, DINNER, c1i, nullptr, nullptr, nullptr,
        y0, y1, y2, nullptr, nullptr, h1i, 512);

    // P9) cg2 + softmax-fuse + gate: fusedg = fused(y,sw)*sigmoid(h1@cg_w2^T)*silu(gate)
    //     A = h1 split, OUT_SPLIT (N=1024,K=512) — 512 blocks
    mgemm_kernel<2, false, false, false, true, true><<<dim3(32, 16), 256, 0, stream>>>(
        h1i, DIMSZ, DIMSZ, c2i, nullptr, nullptr, xz,
        y0, y1, y2, scale_w, nullptr, fgi, 1024);

    // P10) out_proj + residual: outpre = fusedg @ out_pw^T + x (N=512,K=1024)
    mgemm_kernel<0, true, false, false, false, false><<<dim3(32, 8), 256, 0, stream>>>(
        fgi, DINNER, DINNER, opwi, nullptr, x, nullptr,
        nullptr, nullptr, nullptr, nullptr, outpre, nullptr, 512);

    // P11) LayerNorm
    ln_kernel<<<BATCH * SEQ, 256, 0, stream>>>(outpre, ln_gamma, ln_beta, out);
}